// Round 3
// baseline (24019.751 us; speedup 1.0000x reference)
//
#include <hip/hip_runtime.h>
#include <hip/hip_bf16.h>

#define S_DIM 128
#define H_DIM 256
#define A_DIM 8
#define T_STEPS 16
#define BT 8            // batch elements per block
#define HP 264          // padded row length for f32 LDS tiles

// 512 threads: tid = (h<<8) | n ; n = neuron 0..255, h = j-half (0..1).
// Each thread holds W2[n][128h .. 128h+128) in 128 VGPRs (32 float4).
// LIF state (h1,v1,v2) lives on h==0 threads. All accumulation in f64 to
// match the float-accurate numpy reference (f32 products are exact in f64).
// OUTPUT IS FLOAT32 (reference returns jnp.float32).
__global__ __launch_bounds__(512, 2)
void snn_actor_f64(const float* __restrict__ state,
                   const float* __restrict__ W1, const float* __restrict__ b1,
                   const float* __restrict__ W2, const float* __restrict__ b2,
                   const float* __restrict__ W3, const float* __restrict__ b3,
                   float* __restrict__ out)
{
    __shared__ alignas(16) float  st[BT][S_DIM];     // 4 KB state tile
    __shared__ alignas(16) float  s1s[BT][HP];       // 8.25 KB spikes L1
    __shared__ alignas(16) float  s2s[BT][HP];       // 8.25 KB spikes L2
    __shared__ alignas(16) float  w3s[A_DIM][HP];    // 8.25 KB W3 staged
    __shared__ double redh[BT][H_DIM];               // 16 KB h2/h1 partials (h==1 half)
    __shared__ double red3[8][64];                   // 4 KB  h3 chunk partials
    __shared__ unsigned int msk[BT][8];              // 256 B spike bitmasks

    const int tid = threadIdx.x;
    const int n   = tid & 255;
    const int h   = tid >> 8;
    const long b0 = (long)blockIdx.x * BT;

    // ---- stage state tile (1024 f32 = 256 float4) ----
    if (tid < 256) {
        reinterpret_cast<float4*>(&st[0][0])[tid] =
            reinterpret_cast<const float4*>(state + b0 * S_DIM)[tid];
    }
    // ---- stage W3 (2048 f32 = 512 float4; one per thread) ----
    {
        const int a = tid >> 6, c = tid & 63;
        reinterpret_cast<float4*>(&w3s[a][0])[c] =
            reinterpret_cast<const float4*>(W3)[tid];
    }
    __syncthreads();

    // ---- W2 half-row into registers (32 float4 = 128 VGPR) ----
    float4 w2r[32];
    {
        const float4* w2p = reinterpret_cast<const float4*>(W2 + n * H_DIM + h * 128);
        #pragma unroll
        for (int q = 0; q < 32; ++q) w2r[q] = w2p[q];
    }

    // ---- h1 = state @ W1^T + b1 in f64, split by k-half ----
    double hacc[BT];
    #pragma unroll
    for (int bt = 0; bt < BT; ++bt) hacc[bt] = 0.0;
    {
        const float* w1p = W1 + n * S_DIM + h * 64;
        for (int kq = 0; kq < 16; ++kq) {
            float4 w4 = reinterpret_cast<const float4*>(w1p)[kq];
            const double wd0 = (double)w4.x, wd1 = (double)w4.y;
            const double wd2 = (double)w4.z, wd3 = (double)w4.w;
            #pragma unroll
            for (int bt = 0; bt < BT; ++bt) {
                float4 s4 = *reinterpret_cast<const float4*>(&st[bt][h * 64 + kq * 4]);
                double a = hacc[bt];
                a = fma(wd0, (double)s4.x, a);
                a = fma(wd1, (double)s4.y, a);
                a = fma(wd2, (double)s4.z, a);
                a = fma(wd3, (double)s4.w, a);
                hacc[bt] = a;
            }
        }
    }
    if (h) {
        #pragma unroll
        for (int bt = 0; bt < BT; ++bt) redh[bt][n] = hacc[bt];
    }
    __syncthreads();

    double h1r[BT], v1r[BT], v2r[BT];
    const double b2d = h ? 0.0 : (double)b2[n];
    if (!h) {
        const double b1d = (double)b1[n];
        #pragma unroll
        for (int bt = 0; bt < BT; ++bt) {
            h1r[bt] = hacc[bt] + redh[bt][n] + b1d;
            v1r[bt] = 0.0;
            v2r[bt] = 0.0;
        }
    } else {
        #pragma unroll
        for (int bt = 0; bt < BT; ++bt) { h1r[bt] = 0.0; v1r[bt] = 0.0; v2r[bt] = 0.0; }
    }

    // h3 task mapping (threads cooperate 8-way over j)
    const int task  = tid & 63;          // (bt,a)
    const int chunk = tid >> 6;          // j-chunk 0..7 (32 j each)
    const int hbt = task >> 3, ha = task & 7;
    const double b3d = (double)b3[ha];
    double v3r = 0.0;

    for (int t = 0; t < T_STEPS; ++t) {
        // ---- LIF layer 1 (h==0 threads own neurons), spikes + bitmask ----
        if (!h) {
            #pragma unroll
            for (int bt = 0; bt < BT; ++bt) {
                double v = v1r[bt];
                v = v + (h1r[bt] - v) * 0.5;
                const bool sp = (v >= 1.0);
                v1r[bt] = sp ? 0.0 : v;
                s1s[bt][n] = sp ? 1.0f : 0.0f;
                unsigned long long bal = __ballot(sp);
                if ((n & 63) == 0) {
                    const int w = n >> 6;
                    msk[bt][2 * w]     = (unsigned int)bal;
                    msk[bt][2 * w + 1] = (unsigned int)(bal >> 32);
                }
            }
        }
        __syncthreads();

        // ---- h2 partial: thread's 128-j half, skip all-zero spike quads ----
        double acc[BT];
        #pragma unroll
        for (int bt = 0; bt < BT; ++bt) acc[bt] = 0.0;

        unsigned int mm[BT][4];
        #pragma unroll
        for (int bt = 0; bt < BT; ++bt) {
            #pragma unroll
            for (int w = 0; w < 4; ++w)
                mm[bt][w] = __builtin_amdgcn_readfirstlane(msk[bt][4 * h + w]);
        }

        const int jbase = h * 128;
        #pragma unroll
        for (int q = 0; q < 32; ++q) {
            const float4 w4 = w2r[q];
            const double wd0 = (double)w4.x, wd1 = (double)w4.y;
            const double wd2 = (double)w4.z, wd3 = (double)w4.w;
            #pragma unroll
            for (int bt = 0; bt < BT; ++bt) {
                if ((mm[bt][q >> 3] >> ((q & 7) * 4)) & 15u) {   // uniform -> s_cbranch
                    float4 s4 = *reinterpret_cast<const float4*>(&s1s[bt][jbase + q * 4]);
                    double a = acc[bt];
                    a = fma(wd0, (double)s4.x, a);
                    a = fma(wd1, (double)s4.y, a);
                    a = fma(wd2, (double)s4.z, a);
                    a = fma(wd3, (double)s4.w, a);
                    acc[bt] = a;
                }
            }
        }
        if (h) {
            #pragma unroll
            for (int bt = 0; bt < BT; ++bt) redh[bt][n] = acc[bt];
        }
        __syncthreads();

        // ---- LIF layer 2 on h==0 ----
        if (!h) {
            #pragma unroll
            for (int bt = 0; bt < BT; ++bt) {
                const double h2 = acc[bt] + redh[bt][n] + b2d;
                double v = v2r[bt];
                v = v + (h2 - v) * 0.5;
                const bool sp = (v >= 1.0);
                v2r[bt] = sp ? 0.0 : v;
                s2s[bt][n] = sp ? 1.0f : 0.0f;
            }
        }
        __syncthreads();

        // ---- h3 = s2 @ W3^T: 512 threads = 64 tasks x 8 j-chunks ----
        {
            double a3 = 0.0;
            const int j0 = chunk * 32;
            #pragma unroll
            for (int q = 0; q < 8; ++q) {
                float4 w4 = *reinterpret_cast<const float4*>(&w3s[ha][j0 + q * 4]);
                float4 s4 = *reinterpret_cast<const float4*>(&s2s[hbt][j0 + q * 4]);
                a3 = fma((double)w4.x, (double)s4.x, a3);
                a3 = fma((double)w4.y, (double)s4.y, a3);
                a3 = fma((double)w4.z, (double)s4.z, a3);
                a3 = fma((double)w4.w, (double)s4.w, a3);
            }
            red3[chunk][task] = a3;
        }
        __syncthreads();

        // ---- non-spiking integrate on threads 0..63 ----
        if (tid < 64) {
            const double h3 = ((red3[0][task] + red3[1][task]) + (red3[2][task] + red3[3][task]))
                            + ((red3[4][task] + red3[5][task]) + (red3[6][task] + red3[7][task]))
                            + b3d;
            double v = v3r;
            v = v + (h3 - v) * 0.5;
            v3r = v;
        }
    }

    // ---- output: tanh(v3) -> FLOAT32 ----
    if (tid < 64) {
        out[(b0 + hbt) * A_DIM + ha] = (float)tanh(v3r);
    }
}

extern "C" void kernel_launch(void* const* d_in, const int* in_sizes, int n_in,
                              void* d_out, int out_size, void* d_ws, size_t ws_size,
                              hipStream_t stream)
{
    const float* state = (const float*)d_in[0];
    const float* W1    = (const float*)d_in[1];
    const float* b1    = (const float*)d_in[2];
    const float* W2    = (const float*)d_in[3];
    const float* b2    = (const float*)d_in[4];
    const float* W3    = (const float*)d_in[5];
    const float* b3    = (const float*)d_in[6];
    float* out = (float*)d_out;

    const int B = in_sizes[0] / S_DIM;      // 131072
    const int grid = B / BT;                // 16384

    snn_actor_f64<<<grid, 512, 0, stream>>>(state, W1, b1, W2, b2, W3, b3, out);
}